// Round 10
// baseline (1105.995 us; speedup 1.0000x reference)
//
#include <hip/hip_runtime.h>

// Sinkhorn EMD, B=8, N=2048, eps=0.005, 50 iters.
// R28 = R24 champion (442.2us) + ONE change: barrier release by per-wave
// poll. R24's release chain was add(~600cy IC) -> thread0 poll observes
// (~600-1300cy) -> __syncthreads broadcast to 16 waves. R28 keeps the
// arrival __syncthreads (drains vmcnt, quiesces block) + single add by
// thread 0, but EVERY WAVE polls the counter (64 lanes same address =
// one merged IC request/wave/poll) and resumes on its own observation.
// Zero math change (bitwise-identical output), zero added live state
// (respects the spill wall).
// HARD RULES (empirical, this kernel):
//  - NO new per-lane state live across barrier_sync: 4 attempts
//    (R21-R23 arrays/pairing, R27 named scalars) ALL went to scratch at
//    a pinned 64-VGPR allocation (FETCH 16-73MB scratch traffic).
//  - NO math reassociation / term dropping: output sits on a bf16
//    rounding edge (R26: MARGIN 32 -> absmax 1.95e-3 > 1.75e-3).
//  - NO all-lane sparse batching: issued work beats latency (R25).
// Structure (all validated): persistent 256x1024, IC-coherent atomics
// no fences, 4-lane coalesced pot store (R24: WRITE 52->13.6MB),
// counter barrier, online exact-LSE passes 0..3, build at {4,5},
// fixed-shift M = own prev log-sum, MARGIN=48, CAP=256.

#define BB 8
#define NN 2048
#define NPASS 100
#define ONLINE_PASSES 4
#define RPW 4
#define GRID_BLOCKS 256
#define BLOCKS_PER_BATCH 32
#define TPB 1024
#define CAP 256
#define MARGIN 48.0f

constexpr float EPSV = 0.005f;
constexpr float KS   = EPSV * 0.69314718055994531f; // eps*ln2
constexpr float INVK = 1.0f / KS;
constexpr float C1V  = -EPSV * 7.6246189861593985f; // eps*log(1/2048)
constexpr float C1K  = C1V * INVK;
constexpr float KQ4  = KS * 0.25f;
constexpr float TWOI = 2.0f * INVK;
constexpr float HK   = KS * 0.5f;

__device__ __forceinline__ float fexp2(float x) { return __builtin_amdgcn_exp2f(x); }
__device__ __forceinline__ float flog2(float x) { return __builtin_amdgcn_logf(x); }

__device__ __forceinline__ float cohLoad(const float* p) {
    return __hip_atomic_load(p, __ATOMIC_RELAXED, __HIP_MEMORY_SCOPE_AGENT);
}
__device__ __forceinline__ void cohStore(float* p, float v) {
    __hip_atomic_store(p, v, __ATOMIC_RELAXED, __HIP_MEMORY_SCOPE_AGENT);
}
// 4 consecutive row-pots stored by lanes 0..3 as ONE wave instruction:
// 4x4B contiguous = one 32B sector (validated R24: WRITE 52->13.6MB).
__device__ __forceinline__ void potStore4(float* p, int lane,
                                          float o0, float o1, float o2, float o3) {
    if (lane < 4) {
        float ov = (lane == 0) ? o0 : (lane == 1) ? o1 : (lane == 2) ? o2 : o3;
        cohStore(p + lane, ov);
    }
}

// Arrival: block-wide __syncthreads (drains vmcnt -> all stores acked at
// IC) + ONE add by thread 0. Release: every wave polls independently and
// resumes on its own observation (no broadcast __syncthreads). All 64
// lanes load the same address -> one merged request per wave per poll.
__device__ __forceinline__ void barrier_sync(int* ctr, int target) {
    __syncthreads();
    if (threadIdx.x == 0) {
        __hip_atomic_fetch_add(ctr, 1, __ATOMIC_RELAXED, __HIP_MEMORY_SCOPE_AGENT);
    }
    while (__hip_atomic_load(ctr, __ATOMIC_RELAXED, __HIP_MEMORY_SCOPE_AGENT) < target) {
        __builtin_amdgcn_s_sleep(1);
    }
}

__global__ void __launch_bounds__(TPB, 4) emd_persist(
    const float* __restrict__ preds, const float* __restrict__ gts,
    float* __restrict__ fpot, float* __restrict__ gpot,
    float* __restrict__ partials, int* __restrict__ bctr, int* __restrict__ gctr,
    float* __restrict__ out)
{
    __shared__ float4 sjall[2 * NN];          // side0=gts, side1=preds
    __shared__ float  sa[NN];                 // staged pots (dense passes only)
    __shared__ float  wred[16];
    __shared__ unsigned short slist[2][64][CAP];

    const int blk  = blockIdx.x;
    const int b    = blk & 7;
    const int rb   = blk >> 3;
    const int wave = threadIdx.x >> 6;
    const int lane = threadIdx.x & 63;
    const int rowL0 = wave * RPW;             // 0..60
    const int row0  = rb * 64 + rowL0;        // global row base for this wave

    const float* pb  = preds + (size_t)b * NN * 3;
    const float* gbp = gts   + (size_t)b * NN * 3;
    float* fb = fpot + (size_t)b * NN;
    float* gb = gpot + (size_t)b * NN;
    int*   bar = bctr + b * 32;

    for (int t = threadIdx.x; t < NN; t += TPB) {
        float gx = gbp[3*t], gy = gbp[3*t+1], gz = gbp[3*t+2];
        float Gx = gx*TWOI, Gy = gy*TWOI, Gz = gz*TWOI;
        sjall[t] = make_float4(Gx, Gy, Gz, -KQ4*(Gx*Gx+Gy*Gy+Gz*Gz));
        float qx = pb[3*t], qy = pb[3*t+1], qz = pb[3*t+2];
        float Qx = qx*TWOI, Qy = qy*TWOI, Qz = qz*TWOI;
        sjall[NN+t] = make_float4(Qx, Qy, Qz, -KQ4*(Qx*Qx+Qy*Qy+Qz*Qz));
    }
    __syncthreads();

    // wave-resident row constants, both sides (loaded ONCE)
    float qxf[RPW], qyf[RPW], qzf[RPW], pcf[RPW];
    float qxg[RPW], qyg[RPW], qzg[RPW], pcg[RPW];
#pragma unroll
    for (int r = 0; r < RPW; ++r) {
        float4 df = sjall[NN + row0 + r];     // preds rows (f side)
        qxf[r] = HK*df.x; qyf[r] = HK*df.y; qzf[r] = HK*df.z;
        pcf[r] = C1V - KS*df.w;
        float4 dg = sjall[row0 + r];          // gts rows (g side)
        qxg[r] = HK*dg.x; qyg[r] = HK*dg.y; qzg[r] = HK*dg.z;
        pcg[r] = C1V - KS*dg.w;
    }
    float LpF[RPW] = {0,0,0,0}, LpG[RPW] = {0,0,0,0};
    int   cnF[RPW] = {0,0,0,0}, cnG[RPW] = {0,0,0,0};

#pragma unroll 1
    for (int pass = 0; pass < NPASS; ++pass) {
        const int odd = pass & 1;
        const int colOff = odd ? NN : 0;
        const float* pin  = odd ? fb : gb;
        float*       pout = odd ? gb : fb;
        const bool isBuild  = (pass == 4) || (pass == 5);
        const bool isSparse = (pass >= ONLINE_PASSES) && !isBuild;

        float qx[RPW], qy[RPW], qz[RPW], pc[RPW], M[RPW];
#pragma unroll
        for (int r = 0; r < RPW; ++r) {
            qx[r] = odd ? qxg[r] : qxf[r];
            qy[r] = odd ? qyg[r] : qyf[r];
            qz[r] = odd ? qzg[r] : qzf[r];
            pc[r] = odd ? pcg[r] : pcf[r];
            M[r]  = odd ? LpG[r] : LpF[r];
        }

        if (isSparse) {
            // ---- sparse: no staging, no intra-pass sync ----
            float L[RPW];
#pragma unroll
            for (int r = 0; r < RPW; ++r) {
                const int cnt = odd ? cnG[r] : cnF[r];
                const unsigned short* lb = slist[odd][rowL0 + r];
                float s1 = 0.f;
                if (cnt <= CAP) {
#pragma unroll 1
                    for (int k = lane; k < cnt; k += 64) {
                        int j = lb[k];
                        float4 d = sjall[colOff + j];
                        float aw = fmaf(cohLoad(&pin[j]), INVK, d.w);
                        float x  = fmaf(qx[r], d.x, fmaf(qy[r], d.y, fmaf(qz[r], d.z, aw)));
                        s1 += fexp2(fminf(x - M[r], 100.f));
                    }
                } else {
#pragma unroll 1
                    for (int c = 0; c < 32; ++c) {
                        int j = c*64 + lane;
                        float4 d = sjall[colOff + j];
                        float aw = fmaf(cohLoad(&pin[j]), INVK, d.w);
                        float x  = fmaf(qx[r], d.x, fmaf(qy[r], d.y, fmaf(qz[r], d.z, aw)));
                        s1 += fexp2(fminf(x - M[r], 100.f));
                    }
                }
                for (int off = 1; off < 64; off <<= 1) s1 += __shfl_xor(s1, off, 64);
                L[r] = M[r] + flog2(fmaxf(s1, 1e-37f));
            }
#pragma unroll
            for (int r = 0; r < RPW; ++r) {
                if (odd) LpG[r] = L[r]; else LpF[r] = L[r];
            }
            potStore4(&pout[row0], lane, pc[0]-KS*L[0], pc[1]-KS*L[1],
                                         pc[2]-KS*L[2], pc[3]-KS*L[3]);
        } else {
            // ---- dense-type: stage sa, full sweep ----
            for (int t = threadIdx.x; t < NN; t += TPB)
                sa[t] = cohLoad(&pin[t]) * INVK;
            __syncthreads();

            if (pass < ONLINE_PASSES) {
                float m[RPW], s[RPW], Lr[RPW];
#pragma unroll
                for (int r = 0; r < RPW; ++r) { m[r] = -1e30f; s[r] = 0.f; }
#pragma unroll 2
                for (int c = 0; c < 32; ++c) {
                    float4 d = sjall[colOff + c*64 + lane];
                    float aw = d.w + sa[c*64 + lane];
#pragma unroll
                    for (int r = 0; r < RPW; ++r) {
                        float x  = fmaf(qx[r], d.x, fmaf(qy[r], d.y, fmaf(qz[r], d.z, aw)));
                        float mn = fmaxf(m[r], x);
                        s[r] = fmaf(s[r], fexp2(m[r]-mn), fexp2(x-mn));
                        m[r] = mn;
                    }
                }
#pragma unroll
                for (int r = 0; r < RPW; ++r) {
                    float mm = m[r], sv = s[r];
                    for (int off = 1; off < 64; off <<= 1) {
                        float mo = __shfl_xor(mm, off, 64);
                        float so = __shfl_xor(sv, off, 64);
                        float mn = fmaxf(mm, mo);
                        sv = fmaf(sv, fexp2(mm-mn), so * fexp2(mo-mn));
                        mm = mn;
                    }
                    float L = mm + flog2(fmaxf(sv, 1e-37f));
                    Lr[r] = L;
                    if (odd) LpG[r] = L; else LpF[r] = L;
                }
                potStore4(&pout[row0], lane, pc[0]-KS*Lr[0], pc[1]-KS*Lr[1],
                                             pc[2]-KS*Lr[2], pc[3]-KS*Lr[3]);
            } else {
                // build: dense fixed-shift + register-count compaction
                float s[RPW], Lr[RPW]; int cn[RPW];
#pragma unroll
                for (int r = 0; r < RPW; ++r) { s[r] = 0.f; cn[r] = 0; }
#pragma unroll 1
                for (int c = 0; c < 32; ++c) {
                    int j = c*64 + lane;
                    float4 d = sjall[colOff + j];
                    float aw = d.w + sa[j];
#pragma unroll
                    for (int r = 0; r < RPW; ++r) {
                        float x = fmaf(qx[r], d.x, fmaf(qy[r], d.y, fmaf(qz[r], d.z, aw)));
                        s[r] += fexp2(fminf(x - M[r], 100.f));
                        bool pred = (x >= M[r] - MARGIN);
                        unsigned long long mask = __ballot((int)pred);
                        if (pred) {
                            int pos = cn[r] + __popcll(mask & ((1ull << lane) - 1ull));
                            if (pos < CAP) slist[odd][rowL0 + r][pos] = (unsigned short)j;
                        }
                        cn[r] += __popcll(mask);   // wave-uniform
                    }
                }
#pragma unroll
                for (int r = 0; r < RPW; ++r) {
                    float sv = s[r];
                    for (int off = 1; off < 64; off <<= 1) sv += __shfl_xor(sv, off, 64);
                    float L = M[r] + flog2(fmaxf(sv, 1e-37f));
                    Lr[r] = L;
                    if (odd) { LpG[r] = L; cnG[r] = cn[r]; }
                    else     { LpF[r] = L; cnF[r] = cn[r]; }
                }
                potStore4(&pout[row0], lane, pc[0]-KS*Lr[0], pc[1]-KS*Lr[1],
                                             pc[2]-KS*Lr[2], pc[3]-KS*Lr[3]);
            }
        }
        barrier_sync(bar, BLOCKS_PER_BATCH * (pass + 1));
    }

    // ---- dis: sum P*C over f-lists (side 0), direct pot loads ----
    {
        float acc[RPW];
#pragma unroll
        for (int r = 0; r < RPW; ++r) acc[r] = 0.f;
#pragma unroll
        for (int r = 0; r < RPW; ++r) {
            const int cnt = cnF[r];
            const unsigned short* lb = slist[0][rowL0 + r];
            const float bb2 = C1K - LpF[r];
            const float pn  = pcf[r] - C1V;    // |p|^2
            float aa = 0.f;
            if (cnt <= CAP) {
#pragma unroll 1
                for (int k = lane; k < cnt; k += 64) {
                    int j = lb[k];
                    float4 d = sjall[j];
                    float aw = fmaf(cohLoad(&gb[j]), INVK, d.w);
                    float dot = fmaf(qxf[r], d.x, fmaf(qyf[r], d.y, qzf[r]*d.z));
                    float y   = dot + aw + bb2;
                    float e   = fexp2(fminf(y, 80.f));
                    aa = fmaf(e, fmaf(-KS, dot, pn - KS*d.w), aa);
                }
            } else {
#pragma unroll 1
                for (int c = 0; c < 32; ++c) {
                    int j = c*64 + lane;
                    float4 d = sjall[j];
                    float aw = fmaf(cohLoad(&gb[j]), INVK, d.w);
                    float dot = fmaf(qxf[r], d.x, fmaf(qyf[r], d.y, qzf[r]*d.z));
                    float y   = dot + aw + bb2;
                    float e   = fexp2(fminf(y, 80.f));
                    aa = fmaf(e, fmaf(-KS, dot, pn - KS*d.w), aa);
                }
            }
            acc[r] = aa;
        }
        float tot = acc[0] + acc[1] + acc[2] + acc[3];
        for (int off = 1; off < 64; off <<= 1) tot += __shfl_xor(tot, off, 64);
        if (lane == 0) wred[wave] = tot;
        __syncthreads();
        if (threadIdx.x == 0) {
            float v = 0.f;
            for (int w = 0; w < 16; ++w) v += wred[w];
            cohStore(&partials[blk], v);
        }
    }

    barrier_sync(gctr, GRID_BLOCKS);

    if (blk == 0) {
        float v = (threadIdx.x < GRID_BLOCKS) ? cohLoad(&partials[threadIdx.x]) : 0.f;
        for (int off = 1; off < 64; off <<= 1) v += __shfl_xor(v, off, 64);
        if (lane == 0) wred[wave] = v;
        __syncthreads();
        if (threadIdx.x == 0) {
            float t2 = 0.f;
            for (int w = 0; w < 16; ++w) t2 += wred[w];
            out[0] = t2 * (1.0f / BB);
        }
    }
}

extern "C" void kernel_launch(void* const* d_in, const int* in_sizes, int n_in,
                              void* d_out, int out_size, void* d_ws, size_t ws_size,
                              hipStream_t stream) {
    const float* preds = (const float*)d_in[0];
    const float* gts   = (const float*)d_in[1];
    float* fp       = (float*)d_ws;
    float* gp       = fp + BB * NN;
    float* partials = gp + BB * NN;
    int*   bctr     = (int*)(partials + GRID_BLOCKS);
    int*   gctr     = bctr + BB * 32;
    float* out      = (float*)d_out;

    size_t zbytes = (size_t)(2 * BB * NN + GRID_BLOCKS) * sizeof(float)
                  + (size_t)(BB * 32 + 32) * sizeof(int);
    (void)hipMemsetAsync(d_ws, 0, zbytes, stream);

    emd_persist<<<dim3(GRID_BLOCKS), dim3(TPB), 0, stream>>>(
        preds, gts, fp, gp, partials, bctr, gctr, out);
}

// Round 11
// 443.385 us; speedup vs baseline: 2.4944x; 2.4944x over previous
//
#include <hip/hip_runtime.h>

// Sinkhorn EMD, B=8, N=2048, eps=0.005, 50 iters.
// R29 = exact revert to the R24 champion (442.2us measured, absmax
// 9.77e-4, VGPR 64, FETCH 3.6MB, WRITE 13.6MB). This is the session's
// terminal kernel: every remaining lever was tested and eliminated
// with counter evidence.
//   R24 WIN : 4-lane coalesced pot store (WRITE 52->13.6MB, 500->442us).
//   R21/R22/R23/R27 FAIL: ANY added per-lane state live across
//     barrier_sync spills (allocation pinned ~64 VGPR; scratch traffic
//     FETCH 16-73MB; +250-500us) - arrays, paired loops, named scalars
//     all hit the same wall.
//   R25 FAIL: all-lane batched sparse loop - issued-work blowup beats
//     the MLP win; 16 waves/CU of TLP already hides IC gather latency.
//   R26 FAIL: MARGIN 48->32 breaks accuracy (1.95e-3 > 1.75e-3);
//     the math is frozen at bitwise-identical.
//   R28 FAIL: per-wave barrier polling - 512 spinning waves contend
//     with the counter add (442->1106us); thread-0 poll + hardware
//     barrier broadcast is optimal here.
// Remaining time budget (~4.1us/pass): ~56% VALU issue + irreducible
// per-pass chain (IC store-ack drain -> counter round-trip -> dependent
// gather restart) under a hard register wall. Practical floor.
// Structure (all validated): persistent 256x1024, IC-coherent atomics
// no fences, counter barrier (thread-0 poll), register-resident row
// state + per-row sparse gathers w/ direct IC pot loads, online
// exact-LSE passes 0..3, build at {4,5}, fixed-shift M = own prev
// log-sum, MARGIN=48, CAP=256.

#define BB 8
#define NN 2048
#define NPASS 100
#define ONLINE_PASSES 4
#define RPW 4
#define GRID_BLOCKS 256
#define BLOCKS_PER_BATCH 32
#define TPB 1024
#define CAP 256
#define MARGIN 48.0f

constexpr float EPSV = 0.005f;
constexpr float KS   = EPSV * 0.69314718055994531f; // eps*ln2
constexpr float INVK = 1.0f / KS;
constexpr float C1V  = -EPSV * 7.6246189861593985f; // eps*log(1/2048)
constexpr float C1K  = C1V * INVK;
constexpr float KQ4  = KS * 0.25f;
constexpr float TWOI = 2.0f * INVK;
constexpr float HK   = KS * 0.5f;

__device__ __forceinline__ float fexp2(float x) { return __builtin_amdgcn_exp2f(x); }
__device__ __forceinline__ float flog2(float x) { return __builtin_amdgcn_logf(x); }

__device__ __forceinline__ float cohLoad(const float* p) {
    return __hip_atomic_load(p, __ATOMIC_RELAXED, __HIP_MEMORY_SCOPE_AGENT);
}
__device__ __forceinline__ void cohStore(float* p, float v) {
    __hip_atomic_store(p, v, __ATOMIC_RELAXED, __HIP_MEMORY_SCOPE_AGENT);
}
// 4 consecutive row-pots stored by lanes 0..3 as ONE wave instruction:
// 4x4B contiguous = one 32B sector (validated R24: WRITE 52->13.6MB).
__device__ __forceinline__ void potStore4(float* p, int lane,
                                          float o0, float o1, float o2, float o3) {
    if (lane < 4) {
        float ov = (lane == 0) ? o0 : (lane == 1) ? o1 : (lane == 2) ? o2 : o3;
        cohStore(p + lane, ov);
    }
}

__device__ __forceinline__ void barrier_sync(int* ctr, int target) {
    __syncthreads();   // drains vmcnt: all waves' cohStores acked at IC
    if (threadIdx.x == 0) {
        __hip_atomic_fetch_add(ctr, 1, __ATOMIC_RELAXED, __HIP_MEMORY_SCOPE_AGENT);
        while (__hip_atomic_load(ctr, __ATOMIC_RELAXED, __HIP_MEMORY_SCOPE_AGENT) < target) {
            __builtin_amdgcn_s_sleep(1);
        }
    }
    __syncthreads();
}

__global__ void __launch_bounds__(TPB, 4) emd_persist(
    const float* __restrict__ preds, const float* __restrict__ gts,
    float* __restrict__ fpot, float* __restrict__ gpot,
    float* __restrict__ partials, int* __restrict__ bctr, int* __restrict__ gctr,
    float* __restrict__ out)
{
    __shared__ float4 sjall[2 * NN];          // side0=gts, side1=preds
    __shared__ float  sa[NN];                 // staged pots (dense passes only)
    __shared__ float  wred[16];
    __shared__ unsigned short slist[2][64][CAP];

    const int blk  = blockIdx.x;
    const int b    = blk & 7;
    const int rb   = blk >> 3;
    const int wave = threadIdx.x >> 6;
    const int lane = threadIdx.x & 63;
    const int rowL0 = wave * RPW;             // 0..60
    const int row0  = rb * 64 + rowL0;        // global row base for this wave

    const float* pb  = preds + (size_t)b * NN * 3;
    const float* gbp = gts   + (size_t)b * NN * 3;
    float* fb = fpot + (size_t)b * NN;
    float* gb = gpot + (size_t)b * NN;
    int*   bar = bctr + b * 32;

    for (int t = threadIdx.x; t < NN; t += TPB) {
        float gx = gbp[3*t], gy = gbp[3*t+1], gz = gbp[3*t+2];
        float Gx = gx*TWOI, Gy = gy*TWOI, Gz = gz*TWOI;
        sjall[t] = make_float4(Gx, Gy, Gz, -KQ4*(Gx*Gx+Gy*Gy+Gz*Gz));
        float qx = pb[3*t], qy = pb[3*t+1], qz = pb[3*t+2];
        float Qx = qx*TWOI, Qy = qy*TWOI, Qz = qz*TWOI;
        sjall[NN+t] = make_float4(Qx, Qy, Qz, -KQ4*(Qx*Qx+Qy*Qy+Qz*Qz));
    }
    __syncthreads();

    // wave-resident row constants, both sides (loaded ONCE)
    float qxf[RPW], qyf[RPW], qzf[RPW], pcf[RPW];
    float qxg[RPW], qyg[RPW], qzg[RPW], pcg[RPW];
#pragma unroll
    for (int r = 0; r < RPW; ++r) {
        float4 df = sjall[NN + row0 + r];     // preds rows (f side)
        qxf[r] = HK*df.x; qyf[r] = HK*df.y; qzf[r] = HK*df.z;
        pcf[r] = C1V - KS*df.w;
        float4 dg = sjall[row0 + r];          // gts rows (g side)
        qxg[r] = HK*dg.x; qyg[r] = HK*dg.y; qzg[r] = HK*dg.z;
        pcg[r] = C1V - KS*dg.w;
    }
    float LpF[RPW] = {0,0,0,0}, LpG[RPW] = {0,0,0,0};
    int   cnF[RPW] = {0,0,0,0}, cnG[RPW] = {0,0,0,0};

#pragma unroll 1
    for (int pass = 0; pass < NPASS; ++pass) {
        const int odd = pass & 1;
        const int colOff = odd ? NN : 0;
        const float* pin  = odd ? fb : gb;
        float*       pout = odd ? gb : fb;
        const bool isBuild  = (pass == 4) || (pass == 5);
        const bool isSparse = (pass >= ONLINE_PASSES) && !isBuild;

        float qx[RPW], qy[RPW], qz[RPW], pc[RPW], M[RPW];
#pragma unroll
        for (int r = 0; r < RPW; ++r) {
            qx[r] = odd ? qxg[r] : qxf[r];
            qy[r] = odd ? qyg[r] : qyf[r];
            qz[r] = odd ? qzg[r] : qzf[r];
            pc[r] = odd ? pcg[r] : pcf[r];
            M[r]  = odd ? LpG[r] : LpF[r];
        }

        if (isSparse) {
            // ---- sparse: no staging, no intra-pass sync ----
            float L[RPW];
#pragma unroll
            for (int r = 0; r < RPW; ++r) {
                const int cnt = odd ? cnG[r] : cnF[r];
                const unsigned short* lb = slist[odd][rowL0 + r];
                float s1 = 0.f;
                if (cnt <= CAP) {
#pragma unroll 1
                    for (int k = lane; k < cnt; k += 64) {
                        int j = lb[k];
                        float4 d = sjall[colOff + j];
                        float aw = fmaf(cohLoad(&pin[j]), INVK, d.w);
                        float x  = fmaf(qx[r], d.x, fmaf(qy[r], d.y, fmaf(qz[r], d.z, aw)));
                        s1 += fexp2(fminf(x - M[r], 100.f));
                    }
                } else {
#pragma unroll 1
                    for (int c = 0; c < 32; ++c) {
                        int j = c*64 + lane;
                        float4 d = sjall[colOff + j];
                        float aw = fmaf(cohLoad(&pin[j]), INVK, d.w);
                        float x  = fmaf(qx[r], d.x, fmaf(qy[r], d.y, fmaf(qz[r], d.z, aw)));
                        s1 += fexp2(fminf(x - M[r], 100.f));
                    }
                }
                for (int off = 1; off < 64; off <<= 1) s1 += __shfl_xor(s1, off, 64);
                L[r] = M[r] + flog2(fmaxf(s1, 1e-37f));
            }
#pragma unroll
            for (int r = 0; r < RPW; ++r) {
                if (odd) LpG[r] = L[r]; else LpF[r] = L[r];
            }
            potStore4(&pout[row0], lane, pc[0]-KS*L[0], pc[1]-KS*L[1],
                                         pc[2]-KS*L[2], pc[3]-KS*L[3]);
        } else {
            // ---- dense-type: stage sa, full sweep ----
            for (int t = threadIdx.x; t < NN; t += TPB)
                sa[t] = cohLoad(&pin[t]) * INVK;
            __syncthreads();

            if (pass < ONLINE_PASSES) {
                float m[RPW], s[RPW], Lr[RPW];
#pragma unroll
                for (int r = 0; r < RPW; ++r) { m[r] = -1e30f; s[r] = 0.f; }
#pragma unroll 2
                for (int c = 0; c < 32; ++c) {
                    float4 d = sjall[colOff + c*64 + lane];
                    float aw = d.w + sa[c*64 + lane];
#pragma unroll
                    for (int r = 0; r < RPW; ++r) {
                        float x  = fmaf(qx[r], d.x, fmaf(qy[r], d.y, fmaf(qz[r], d.z, aw)));
                        float mn = fmaxf(m[r], x);
                        s[r] = fmaf(s[r], fexp2(m[r]-mn), fexp2(x-mn));
                        m[r] = mn;
                    }
                }
#pragma unroll
                for (int r = 0; r < RPW; ++r) {
                    float mm = m[r], sv = s[r];
                    for (int off = 1; off < 64; off <<= 1) {
                        float mo = __shfl_xor(mm, off, 64);
                        float so = __shfl_xor(sv, off, 64);
                        float mn = fmaxf(mm, mo);
                        sv = fmaf(sv, fexp2(mm-mn), so * fexp2(mo-mn));
                        mm = mn;
                    }
                    float L = mm + flog2(fmaxf(sv, 1e-37f));
                    Lr[r] = L;
                    if (odd) LpG[r] = L; else LpF[r] = L;
                }
                potStore4(&pout[row0], lane, pc[0]-KS*Lr[0], pc[1]-KS*Lr[1],
                                             pc[2]-KS*Lr[2], pc[3]-KS*Lr[3]);
            } else {
                // build: dense fixed-shift + register-count compaction
                float s[RPW], Lr[RPW]; int cn[RPW];
#pragma unroll
                for (int r = 0; r < RPW; ++r) { s[r] = 0.f; cn[r] = 0; }
#pragma unroll 1
                for (int c = 0; c < 32; ++c) {
                    int j = c*64 + lane;
                    float4 d = sjall[colOff + j];
                    float aw = d.w + sa[j];
#pragma unroll
                    for (int r = 0; r < RPW; ++r) {
                        float x = fmaf(qx[r], d.x, fmaf(qy[r], d.y, fmaf(qz[r], d.z, aw)));
                        s[r] += fexp2(fminf(x - M[r], 100.f));
                        bool pred = (x >= M[r] - MARGIN);
                        unsigned long long mask = __ballot((int)pred);
                        if (pred) {
                            int pos = cn[r] + __popcll(mask & ((1ull << lane) - 1ull));
                            if (pos < CAP) slist[odd][rowL0 + r][pos] = (unsigned short)j;
                        }
                        cn[r] += __popcll(mask);   // wave-uniform
                    }
                }
#pragma unroll
                for (int r = 0; r < RPW; ++r) {
                    float sv = s[r];
                    for (int off = 1; off < 64; off <<= 1) sv += __shfl_xor(sv, off, 64);
                    float L = M[r] + flog2(fmaxf(sv, 1e-37f));
                    Lr[r] = L;
                    if (odd) { LpG[r] = L; cnG[r] = cn[r]; }
                    else     { LpF[r] = L; cnF[r] = cn[r]; }
                }
                potStore4(&pout[row0], lane, pc[0]-KS*Lr[0], pc[1]-KS*Lr[1],
                                             pc[2]-KS*Lr[2], pc[3]-KS*Lr[3]);
            }
        }
        barrier_sync(bar, BLOCKS_PER_BATCH * (pass + 1));
    }

    // ---- dis: sum P*C over f-lists (side 0), direct pot loads ----
    {
        float acc[RPW];
#pragma unroll
        for (int r = 0; r < RPW; ++r) acc[r] = 0.f;
#pragma unroll
        for (int r = 0; r < RPW; ++r) {
            const int cnt = cnF[r];
            const unsigned short* lb = slist[0][rowL0 + r];
            const float bb2 = C1K - LpF[r];
            const float pn  = pcf[r] - C1V;    // |p|^2
            float aa = 0.f;
            if (cnt <= CAP) {
#pragma unroll 1
                for (int k = lane; k < cnt; k += 64) {
                    int j = lb[k];
                    float4 d = sjall[j];
                    float aw = fmaf(cohLoad(&gb[j]), INVK, d.w);
                    float dot = fmaf(qxf[r], d.x, fmaf(qyf[r], d.y, qzf[r]*d.z));
                    float y   = dot + aw + bb2;
                    float e   = fexp2(fminf(y, 80.f));
                    aa = fmaf(e, fmaf(-KS, dot, pn - KS*d.w), aa);
                }
            } else {
#pragma unroll 1
                for (int c = 0; c < 32; ++c) {
                    int j = c*64 + lane;
                    float4 d = sjall[j];
                    float aw = fmaf(cohLoad(&gb[j]), INVK, d.w);
                    float dot = fmaf(qxf[r], d.x, fmaf(qyf[r], d.y, qzf[r]*d.z));
                    float y   = dot + aw + bb2;
                    float e   = fexp2(fminf(y, 80.f));
                    aa = fmaf(e, fmaf(-KS, dot, pn - KS*d.w), aa);
                }
            }
            acc[r] = aa;
        }
        float tot = acc[0] + acc[1] + acc[2] + acc[3];
        for (int off = 1; off < 64; off <<= 1) tot += __shfl_xor(tot, off, 64);
        if (lane == 0) wred[wave] = tot;
        __syncthreads();
        if (threadIdx.x == 0) {
            float v = 0.f;
            for (int w = 0; w < 16; ++w) v += wred[w];
            cohStore(&partials[blk], v);
        }
    }

    barrier_sync(gctr, GRID_BLOCKS);

    if (blk == 0) {
        float v = (threadIdx.x < GRID_BLOCKS) ? cohLoad(&partials[threadIdx.x]) : 0.f;
        for (int off = 1; off < 64; off <<= 1) v += __shfl_xor(v, off, 64);
        if (lane == 0) wred[wave] = v;
        __syncthreads();
        if (threadIdx.x == 0) {
            float t2 = 0.f;
            for (int w = 0; w < 16; ++w) t2 += wred[w];
            out[0] = t2 * (1.0f / BB);
        }
    }
}

extern "C" void kernel_launch(void* const* d_in, const int* in_sizes, int n_in,
                              void* d_out, int out_size, void* d_ws, size_t ws_size,
                              hipStream_t stream) {
    const float* preds = (const float*)d_in[0];
    const float* gts   = (const float*)d_in[1];
    float* fp       = (float*)d_ws;
    float* gp       = fp + BB * NN;
    float* partials = gp + BB * NN;
    int*   bctr     = (int*)(partials + GRID_BLOCKS);
    int*   gctr     = bctr + BB * 32;
    float* out      = (float*)d_out;

    size_t zbytes = (size_t)(2 * BB * NN + GRID_BLOCKS) * sizeof(float)
                  + (size_t)(BB * 32 + 32) * sizeof(int);
    (void)hipMemsetAsync(d_ws, 0, zbytes, stream);

    emd_persist<<<dim3(GRID_BLOCKS), dim3(TPB), 0, stream>>>(
        preds, gts, fp, gp, partials, bctr, gctr, out);
}